// Round 3
// baseline (3813.882 us; speedup 1.0000x reference)
//
#include <hip/hip_runtime.h>
#include <hip/hip_bf16.h>
#include <math.h>

#define B_ 64
#define S_ 512
#define I_ 512
#define H_ 1024

typedef __attribute__((ext_vector_type(8))) short short8;
typedef __attribute__((ext_vector_type(4))) short short4v;
typedef __attribute__((ext_vector_type(4))) float f32x4;

__device__ inline short bf16bits(float f) {
    __hip_bfloat16 h = __float2bfloat16(f);
    return __builtin_bit_cast(short, h);
}

// ---------------- Phase A: x_proj = X @ W_ih^T + (b_ih + b_hh) -> d_out ----------------
#define BM 128
#define BN 128
#define BK 32
#define LDT 40   // padded LDS row (32 + 8 bf16)

__global__ __launch_bounds__(256) void xproj_gemm(const float* __restrict__ X,
                                                  const float* __restrict__ Wih,
                                                  const float* __restrict__ bih,
                                                  const float* __restrict__ bhh,
                                                  float* __restrict__ out) {
    __shared__ __hip_bfloat16 sA[BM * LDT];
    __shared__ __hip_bfloat16 sB[BN * LDT];
    const int tid  = threadIdx.x;
    const int m0   = blockIdx.x * BM;
    const int n0   = blockIdx.y * BN;
    const int wave = tid >> 6;
    const int lane = tid & 63;
    const int quad = lane >> 4;
    const int l16  = lane & 15;
    const int wm   = (wave >> 1) * 64;
    const int wn   = (wave & 1) * 64;

    f32x4 acc[4][4] = {};

    for (int k0 = 0; k0 < I_; k0 += BK) {
#pragma unroll
        for (int i = 0; i < 4; ++i) {
            int idx = tid + i * 256;
            int r   = idx >> 3;
            int c4  = idx & 7;
            f32x4 a = *reinterpret_cast<const f32x4*>(X   + (size_t)(m0 + r) * I_ + k0 + c4 * 4);
            f32x4 b = *reinterpret_cast<const f32x4*>(Wih + (size_t)(n0 + r) * I_ + k0 + c4 * 4);
            short4v ap, bp;
            ap[0] = bf16bits(a[0]); ap[1] = bf16bits(a[1]); ap[2] = bf16bits(a[2]); ap[3] = bf16bits(a[3]);
            bp[0] = bf16bits(b[0]); bp[1] = bf16bits(b[1]); bp[2] = bf16bits(b[2]); bp[3] = bf16bits(b[3]);
            int off = r * LDT + c4 * 4;
            *reinterpret_cast<short4v*>(&sA[off]) = ap;
            *reinterpret_cast<short4v*>(&sB[off]) = bp;
        }
        __syncthreads();

        short8 af[4], bf[4];
#pragma unroll
        for (int mt = 0; mt < 4; ++mt)
            af[mt] = *reinterpret_cast<const short8*>(&sA[(wm + mt * 16 + l16) * LDT + quad * 8]);
#pragma unroll
        for (int nt = 0; nt < 4; ++nt)
            bf[nt] = *reinterpret_cast<const short8*>(&sB[(wn + nt * 16 + l16) * LDT + quad * 8]);
#pragma unroll
        for (int mt = 0; mt < 4; ++mt)
#pragma unroll
            for (int nt = 0; nt < 4; ++nt)
                acc[mt][nt] = __builtin_amdgcn_mfma_f32_16x16x32_bf16(af[mt], bf[nt], acc[mt][nt], 0, 0, 0);
        __syncthreads();
    }

#pragma unroll
    for (int mt = 0; mt < 4; ++mt) {
#pragma unroll
        for (int nt = 0; nt < 4; ++nt) {
            int gm = m0 + wm + mt * 16 + quad * 4;
            int gn = n0 + wn + nt * 16 + l16;
            float bias = bih[gn] + bhh[gn];
#pragma unroll
            for (int r = 0; r < 4; ++r)
                out[(size_t)(gm + r) * H_ + gn] = acc[mt][nt][r] + bias;
        }
    }
}

// ---------------- Phase B: persistent recurrent kernel ----------------
// 256 blocks = 4 groups (16 batches) x 64 j-blocks (16 cols).
// Round-3 sync protocol — per-WAVE epoch flags, zero atomic RMWs:
//  - h stores: 4B agent-scope RELAXED sc1 stores (live at MALL, never dirty L2).
//  - each wave: h store -> wave-local s_waitcnt vmcnt(0) -> lane0 stores its
//    epoch flag (relaxed, one-way, distinct address per wave -> no contention).
//  - out[] store AFTER the flag: keeps the fp32 store ack off the critical path.
//  - consumer: wave0 polls all 64 blocks x 4 wave-flags (4 sc1 dword loads/lane,
//    __all over 64 lanes), then ONE acquire load (single buffer_inv), barrier.
//  - NO release fences, NO threadfence, NO fetch_add anywhere in the loop.
#define WLD 1032   // padded LDS row for W (1024 + 8)

__global__ __launch_bounds__(256) void rnn_steps(const float* __restrict__ Whh,
                                                 float* __restrict__ out,
                                                 unsigned short* __restrict__ hbuf,
                                                 unsigned int* __restrict__ flags) {
    __shared__ __hip_bfloat16 Wl[16 * WLD];
    __shared__ float red[4][16][17];
    const int tid  = threadIdx.x;
    const int bid  = blockIdx.x;
    const int g    = bid >> 6;        // batch group 0..3
    const int jblk = bid & 63;        // j block 0..63
    const int j0   = jblk * 16;
    const int b0   = g * 16;
    const int wave = tid >> 6;
    const int lane = tid & 63;
    const int quad = lane >> 4;
    const int l16  = lane & 15;
    const int m    = tid >> 4;        // batch within tile
    const int n    = tid & 15;        // j within tile

    // stage W_hh rows j0..j0+15 fp32 -> bf16 LDS
    for (int idx = tid; idx < 16 * 256; idx += 256) {
        int r  = idx >> 8;
        int c4 = idx & 255;
        f32x4 w = *reinterpret_cast<const f32x4*>(Whh + (size_t)(j0 + r) * H_ + c4 * 4);
        short4v wp;
        wp[0] = bf16bits(w[0]); wp[1] = bf16bits(w[1]); wp[2] = bf16bits(w[2]); wp[3] = bf16bits(w[3]);
        *reinterpret_cast<short4v*>(&Wl[r * WLD + c4 * 4]) = wp;
    }
    __syncthreads();

    const size_t orow = (size_t)(b0 + m) * S_ * H_ + (j0 + n);
    unsigned int* fgrp = flags + g * 256;           // this group's 256 wave-flags
    unsigned int* myflag = fgrp + jblk * 4 + wave;  // this wave's flag

    for (int t = 0; t < S_; ++t) {
        // prefetch x_proj for this step (independent of h) — overlaps the spin
        float xp = __builtin_nontemporal_load(out + orow + (size_t)t * H_);
        float s = 0.f;

        if (t > 0) {
            if (wave == 0) {
                const unsigned int target = (unsigned int)t;
                const unsigned int* fl = fgrp + lane * 4;   // block `lane`'s 4 wave-flags
                int guard = 0;
                bool ok;
                do {
                    unsigned int f0 = __hip_atomic_load(fl + 0, __ATOMIC_RELAXED, __HIP_MEMORY_SCOPE_AGENT);
                    unsigned int f1 = __hip_atomic_load(fl + 1, __ATOMIC_RELAXED, __HIP_MEMORY_SCOPE_AGENT);
                    unsigned int f2 = __hip_atomic_load(fl + 2, __ATOMIC_RELAXED, __HIP_MEMORY_SCOPE_AGENT);
                    unsigned int f3 = __hip_atomic_load(fl + 3, __ATOMIC_RELAXED, __HIP_MEMORY_SCOPE_AGENT);
                    ok = (f0 >= target) & (f1 >= target) & (f2 >= target) & (f3 >= target);
                } while (!__all(ok) && ++guard < 2000000);
                // single acquire (one buffer_inv) now that all producers arrived
                (void)__hip_atomic_load(fl, __ATOMIC_ACQUIRE, __HIP_MEMORY_SCOPE_AGENT);
            }
            __syncthreads();   // #1: release all waves; caches invalidated

            const unsigned short* hprev = hbuf + (size_t)((t - 1) & 1) * (B_ * H_);
            f32x4 acc = {0.f, 0.f, 0.f, 0.f};
            const int kbase = wave * 256;
#pragma unroll
            for (int i = 0; i < 8; ++i) {
                int k = kbase + i * 32 + quad * 8;
                short8 av = *reinterpret_cast<const short8*>(hprev + (size_t)(b0 + l16) * H_ + k);
                short8 bv = *reinterpret_cast<const short8*>(&Wl[l16 * WLD + k]);
                acc = __builtin_amdgcn_mfma_f32_16x16x32_bf16(av, bv, acc, 0, 0, 0);
            }
#pragma unroll
            for (int r = 0; r < 4; ++r)
                red[wave][quad * 4 + r][l16] = acc[r];
            __syncthreads();   // #2: reduction staged

            s = red[0][m][n] + red[1][m][n] + red[2][m][n] + red[3][m][n];
        }

        float val = tanhf(xp + s);

        if (t < S_ - 1) {
            // pack (n, n+1) bf16 pair via lane shuffle; even-n lanes store 4B sc1
            float nb = __shfl_xor(val, 1, 64);
            unsigned int pair = ((unsigned int)(unsigned short)bf16bits(nb) << 16)
                              | (unsigned int)(unsigned short)bf16bits(val);
            if ((n & 1) == 0) {
                unsigned int* dst = (unsigned int*)(hbuf + (size_t)(t & 1) * (B_ * H_)
                                                    + (size_t)(b0 + m) * H_ + (j0 + n));
                __hip_atomic_store(dst, pair, __ATOMIC_RELAXED, __HIP_MEMORY_SCOPE_AGENT);
            }
            // wave-local drain of the h stores, then one-way flag store
            asm volatile("s_waitcnt vmcnt(0)" ::: "memory");
            if (lane == 0)
                __hip_atomic_store(myflag, (unsigned int)(t + 1), __ATOMIC_RELAXED, __HIP_MEMORY_SCOPE_AGENT);
        }

        // out store AFTER the flag — its ack is off the critical path
        __builtin_nontemporal_store(val, out + orow + (size_t)t * H_);
    }
}

extern "C" void kernel_launch(void* const* d_in, const int* in_sizes, int n_in,
                              void* d_out, int out_size, void* d_ws, size_t ws_size,
                              hipStream_t stream) {
    const float* x   = (const float*)d_in[0];   // (B,S,I)
    const float* Wih = (const float*)d_in[1];   // (H,I)
    const float* Whh = (const float*)d_in[2];   // (H,H)
    const float* bih = (const float*)d_in[3];   // (H)
    const float* bhh = (const float*)d_in[4];   // (H)
    float* out = (float*)d_out;                 // (B,S,H)

    unsigned int* flags = (unsigned int*)d_ws;                      // 4 groups x 256 wave-flags = 4 KB
    unsigned short* hbuf = (unsigned short*)((char*)d_ws + 4096);   // 2 x 64 x 1024 bf16

    hipMemsetAsync(d_ws, 0, 4096, stream);      // zero flags every call

    dim3 gA(256, 8);
    xproj_gemm<<<gA, 256, 0, stream>>>(x, Wih, bih, bhh, out);
    rnn_steps<<<256, 256, 0, stream>>>(Whh, out, hbuf, flags);
}

// Round 4
// 3209.566 us; speedup vs baseline: 1.1883x; 1.1883x over previous
//
#include <hip/hip_runtime.h>
#include <hip/hip_bf16.h>
#include <math.h>

#define B_ 64
#define S_ 512
#define I_ 512
#define H_ 1024

typedef __attribute__((ext_vector_type(8))) short short8;
typedef __attribute__((ext_vector_type(4))) short short4v;
typedef __attribute__((ext_vector_type(4))) float f32x4;

__device__ inline short bf16bits(float f) {
    __hip_bfloat16 h = __float2bfloat16(f);
    return __builtin_bit_cast(short, h);
}

// ---------------- Phase A: x_proj = X @ W_ih^T + (b_ih + b_hh) -> d_out ----------------
#define BM 128
#define BN 128
#define BK 32
#define LDT 40   // padded LDS row (32 + 8 bf16)

__global__ __launch_bounds__(256) void xproj_gemm(const float* __restrict__ X,
                                                  const float* __restrict__ Wih,
                                                  const float* __restrict__ bih,
                                                  const float* __restrict__ bhh,
                                                  float* __restrict__ out) {
    __shared__ __hip_bfloat16 sA[BM * LDT];
    __shared__ __hip_bfloat16 sB[BN * LDT];
    const int tid  = threadIdx.x;
    const int m0   = blockIdx.x * BM;
    const int n0   = blockIdx.y * BN;
    const int wave = tid >> 6;
    const int lane = tid & 63;
    const int quad = lane >> 4;
    const int l16  = lane & 15;
    const int wm   = (wave >> 1) * 64;
    const int wn   = (wave & 1) * 64;

    f32x4 acc[4][4] = {};

    for (int k0 = 0; k0 < I_; k0 += BK) {
#pragma unroll
        for (int i = 0; i < 4; ++i) {
            int idx = tid + i * 256;
            int r   = idx >> 3;
            int c4  = idx & 7;
            f32x4 a = *reinterpret_cast<const f32x4*>(X   + (size_t)(m0 + r) * I_ + k0 + c4 * 4);
            f32x4 b = *reinterpret_cast<const f32x4*>(Wih + (size_t)(n0 + r) * I_ + k0 + c4 * 4);
            short4v ap, bp;
            ap[0] = bf16bits(a[0]); ap[1] = bf16bits(a[1]); ap[2] = bf16bits(a[2]); ap[3] = bf16bits(a[3]);
            bp[0] = bf16bits(b[0]); bp[1] = bf16bits(b[1]); bp[2] = bf16bits(b[2]); bp[3] = bf16bits(b[3]);
            int off = r * LDT + c4 * 4;
            *reinterpret_cast<short4v*>(&sA[off]) = ap;
            *reinterpret_cast<short4v*>(&sB[off]) = bp;
        }
        __syncthreads();

        short8 af[4], bf[4];
#pragma unroll
        for (int mt = 0; mt < 4; ++mt)
            af[mt] = *reinterpret_cast<const short8*>(&sA[(wm + mt * 16 + l16) * LDT + quad * 8]);
#pragma unroll
        for (int nt = 0; nt < 4; ++nt)
            bf[nt] = *reinterpret_cast<const short8*>(&sB[(wn + nt * 16 + l16) * LDT + quad * 8]);
#pragma unroll
        for (int mt = 0; mt < 4; ++mt)
#pragma unroll
            for (int nt = 0; nt < 4; ++nt)
                acc[mt][nt] = __builtin_amdgcn_mfma_f32_16x16x32_bf16(af[mt], bf[nt], acc[mt][nt], 0, 0, 0);
        __syncthreads();
    }

#pragma unroll
    for (int mt = 0; mt < 4; ++mt) {
#pragma unroll
        for (int nt = 0; nt < 4; ++nt) {
            int gm = m0 + wm + mt * 16 + quad * 4;
            int gn = n0 + wn + nt * 16 + l16;
            float bias = bih[gn] + bhh[gn];
#pragma unroll
            for (int r = 0; r < 4; ++r)
                out[(size_t)(gm + r) * H_ + gn] = acc[mt][nt][r] + bias;
        }
    }
}

// ---------------- Phase B: persistent recurrent kernel ----------------
// Round-4 structure: 64 blocks = 4 groups (16 batches) x 16 blocks (64 cols each).
//  - W slice 64x1024 bf16 stationary in LDS (132 KB, 1 block/CU).
//  - column-split waves: wave w owns cols [w*16, w*16+16), full K=1024, 32 MFMAs,
//    2 interleaved acc chains. NO cross-wave reduction, NO barrier #2.
//  - per-WAVE one-way epoch flags (64/group, 64-B spaced, zero RMWs).
//  - consumer: ONLY wave 0 polls (64 lanes x 1 relaxed load), then one acquire
//    (single cache-inv), one __syncthreads to release. ~16x lighter polling than R3.
//  - h stores sc1 relaxed -> wave-local vmcnt(0) -> flag store. out[] after flag.
#define WLD 1032   // padded LDS row for W (1024 + 8 bf16)

__global__ __launch_bounds__(256) void rnn_steps(const float* __restrict__ Whh,
                                                 float* __restrict__ out,
                                                 unsigned short* __restrict__ hbuf,
                                                 unsigned int* __restrict__ flags) {
    __shared__ __hip_bfloat16 Wl[64 * WLD];   // 132 KB
    const int tid  = threadIdx.x;
    const int bid  = blockIdx.x;   // 64 blocks
    const int g    = bid >> 4;     // group 0..3
    const int blk  = bid & 15;     // 0..15
    const int j0   = blk * 64;     // first col of this block
    const int b0   = g * 16;       // first batch of this group
    const int wave = tid >> 6;
    const int lane = tid & 63;
    const int quad = lane >> 4;
    const int l16  = lane & 15;
    const int lcol = wave * 16 + l16;   // local col 0..63

    // stage W_hh rows j0..j0+63 fp32 -> bf16 LDS
    for (int idx = tid; idx < 64 * 256; idx += 256) {
        int r  = idx >> 8;        // 0..63
        int c4 = idx & 255;       // float4 group
        f32x4 w = *reinterpret_cast<const f32x4*>(Whh + (size_t)(j0 + r) * H_ + c4 * 4);
        short4v wp;
        wp[0] = bf16bits(w[0]); wp[1] = bf16bits(w[1]); wp[2] = bf16bits(w[2]); wp[3] = bf16bits(w[3]);
        *reinterpret_cast<short4v*>(&Wl[r * WLD + c4 * 4]) = wp;
    }
    __syncthreads();

    unsigned int* fgrp   = flags + (size_t)g * 64 * 16;            // 64 flags, 64-B spaced
    unsigned int* myflag = fgrp + (size_t)(blk * 4 + wave) * 16;

    // this lane's 4 outputs: batch = quad*4+r, col = j0 + lcol
    const size_t obase = (size_t)(b0 + quad * 4) * S_ * H_ + j0 + lcol;

    for (int t = 0; t < S_; ++t) {
        // prefetch x_proj for this step — overlaps the spin
        float xp[4];
#pragma unroll
        for (int r = 0; r < 4; ++r)
            xp[r] = __builtin_nontemporal_load(out + obase + (size_t)r * (S_ * H_) + (size_t)t * H_);

        f32x4 sum = {0.f, 0.f, 0.f, 0.f};
        if (t > 0) {
            if (wave == 0) {
                unsigned int* fl = fgrp + (size_t)lane * 16;   // one flag per lane
                const unsigned int target = (unsigned int)t;
                int guard = 0;
                bool ok;
                do {
                    unsigned int v = __hip_atomic_load(fl, __ATOMIC_RELAXED, __HIP_MEMORY_SCOPE_AGENT);
                    ok = (v >= target);
                } while (!__all(ok) && ++guard < 2000000);
                // single acquire: invalidate stale L1/L2 once
                (void)__hip_atomic_load(fl, __ATOMIC_ACQUIRE, __HIP_MEMORY_SCOPE_AGENT);
            }
            __syncthreads();   // release all waves; caches fresh

            const unsigned short* hprev = hbuf + (size_t)((t - 1) & 1) * (B_ * H_);
            const unsigned short* hrow  = hprev + (size_t)(b0 + l16) * H_;
            const __hip_bfloat16* wrow  = &Wl[lcol * WLD];
            f32x4 acc0 = {0.f, 0.f, 0.f, 0.f};
            f32x4 acc1 = {0.f, 0.f, 0.f, 0.f};
#pragma unroll
            for (int i = 0; i < 16; ++i) {
                int ka = i * 32 + quad * 8;
                int kb = ka + 512;
                short8 a0 = *reinterpret_cast<const short8*>(hrow + ka);
                short8 w0 = *reinterpret_cast<const short8*>(wrow + ka);
                acc0 = __builtin_amdgcn_mfma_f32_16x16x32_bf16(a0, w0, acc0, 0, 0, 0);
                short8 a1 = *reinterpret_cast<const short8*>(hrow + kb);
                short8 w1 = *reinterpret_cast<const short8*>(wrow + kb);
                acc1 = __builtin_amdgcn_mfma_f32_16x16x32_bf16(a1, w1, acc1, 0, 0, 0);
            }
            sum = acc0 + acc1;
        }

        float val[4];
#pragma unroll
        for (int r = 0; r < 4; ++r)
            val[r] = tanhf(xp[r] + sum[r]);

        if (t < S_ - 1) {
            unsigned short* hcur = hbuf + (size_t)(t & 1) * (B_ * H_);
#pragma unroll
            for (int r = 0; r < 4; ++r) {
                // pack (col, col+1) bf16 pair via lane shuffle; even-col lanes store 4B
                float nb = __shfl_xor(val[r], 1, 64);
                unsigned int pair = ((unsigned int)(unsigned short)bf16bits(nb) << 16)
                                  | (unsigned int)(unsigned short)bf16bits(val[r]);
                if ((l16 & 1) == 0) {
                    unsigned int* dst = (unsigned int*)(hcur + (size_t)(b0 + quad * 4 + r) * H_ + j0 + lcol);
                    __hip_atomic_store(dst, pair, __ATOMIC_RELAXED, __HIP_MEMORY_SCOPE_AGENT);
                }
            }
            // wave-local drain of h stores, then one-way epoch flag
            asm volatile("s_waitcnt vmcnt(0)" ::: "memory");
            if (lane == 0)
                __hip_atomic_store(myflag, (unsigned int)(t + 1), __ATOMIC_RELAXED, __HIP_MEMORY_SCOPE_AGENT);
        }

        // out stores AFTER the flag — ack off the critical path
#pragma unroll
        for (int r = 0; r < 4; ++r)
            __builtin_nontemporal_store(val[r], out + obase + (size_t)r * (S_ * H_) + (size_t)t * H_);
    }
}

extern "C" void kernel_launch(void* const* d_in, const int* in_sizes, int n_in,
                              void* d_out, int out_size, void* d_ws, size_t ws_size,
                              hipStream_t stream) {
    const float* x   = (const float*)d_in[0];   // (B,S,I)
    const float* Wih = (const float*)d_in[1];   // (H,I)
    const float* Whh = (const float*)d_in[2];   // (H,H)
    const float* bih = (const float*)d_in[3];   // (H)
    const float* bhh = (const float*)d_in[4];   // (H)
    float* out = (float*)d_out;                 // (B,S,H)

    unsigned int* flags = (unsigned int*)d_ws;                       // 4 x 64 flags x 64 B = 16 KB
    unsigned short* hbuf = (unsigned short*)((char*)d_ws + 16384);   // 2 x 64 x 1024 bf16

    hipMemsetAsync(d_ws, 0, 16384, stream);     // zero flags every call

    dim3 gA(256, 8);
    xproj_gemm<<<gA, 256, 0, stream>>>(x, Wih, bih, bhh, out);
    rnn_steps<<<64, 256, 0, stream>>>(Whh, out, hbuf, flags);
}